// Round 1
// baseline (458.076 us; speedup 1.0000x reference)
//
#include <hip/hip_runtime.h>
#include <hip/hip_bf16.h>
#include <math.h>

// Problem constants
#define BB   32
#define HH   40
#define WW   256
#define NF   40          // FREQ
#define C1N  64
#define H1N  36
#define W1N  252
#define KCNN 580608      // 64*36*252
#define NB2  284         // gemm split-K blocks
#define KPB  2048        // k per gemm block

// ---------------- K0: transpose w1 [c1][c0][ki][kj] -> w1t [c0][ki][kj][c1] ----------------
__global__ void k0_transpose_w1(const float* __restrict__ w1, float* __restrict__ w1t) {
    int o = blockIdx.x * 256 + threadIdx.x;      // 72*256 = 18432 = 32*9*64
    int c1 = o & 63;
    int rest = o >> 6;                            // ((c0*3+ki)*3+kj)
    int kj = rest % 3;
    int ki = (rest / 3) % 3;
    int c0 = rest / 9;
    w1t[o] = w1[(c1 * 32 + c0) * 9 + ki * 3 + kj];
}

// ---------------- K1: fused conv0(relu) + conv1(relu) -> x (bf16) ----------------
// grid (4 j-tiles, 9 i-tiles, 32 b), block 256 (4 waves).
// LDS: y0 tile [32 c0][6 rows][66 cols] f32 = 50688 B.
// Each wave owns 16 output channels (c1 = wave*16 + cc) -> big register tile keeps
// LDS traffic (18 b32 / c0 / wave) far under the 1152 VALU cycles / c0 / wave.
__global__ __launch_bounds__(256) void k1_conv(
        const float* __restrict__ inp, const float* __restrict__ w0,
        const float* __restrict__ b0, const float* __restrict__ w1t,
        const float* __restrict__ b1, __hip_bfloat16* __restrict__ xbf) {
    __shared__ float y0s[32 * 396];   // 396 = 6*66

    const int jt = blockIdx.x;        // 0..3  -> j0 = 64*jt
    const int it = blockIdx.y;        // 0..8  -> i0 = 4*it
    const int b  = blockIdx.z;
    const int i0 = it * 4;
    const int j0 = jt * 64;
    const int tid = threadIdx.x;

    // ---- stage y0 = relu(conv0 + b0) for rows i0..i0+5, cols j0..j0+65 ----
    {
        const int c0  = tid >> 3;     // 0..31
        const int sub = tid & 7;
        float wreg[9];
        #pragma unroll
        for (int k = 0; k < 9; ++k) wreg[k] = w0[c0 * 9 + k];
        const float bias = b0[c0];
        const float* ibase = inp + b * HH * WW;
        for (int s = 0; s < 50; ++s) {
            int pos = sub + 8 * s;                 // 0..395
            if (pos < 396) {
                int r   = pos / 66;
                int col = pos - r * 66;
                int gy  = i0 + r;                  // <= 37 (valid, H0=38)
                int gc  = j0 + col;                // may exceed 253 on last tile
                float v = 0.0f;
                if (gc < 254) {                    // inputs cols gc..gc+2 <= 255: in range
                    float a = bias;
                    #pragma unroll
                    for (int ki = 0; ki < 3; ++ki)
                        #pragma unroll
                        for (int kj = 0; kj < 3; ++kj)
                            a = fmaf(ibase[(gy + ki) * WW + gc + kj], wreg[ki * 3 + kj], a);
                    v = fmaxf(a, 0.0f);
                }
                y0s[c0 * 396 + pos] = v;
            }
        }
    }
    __syncthreads();

    // ---- conv1 main loop ----
    const int lane = tid & 63;
    const int ty   = tid >> 6;        // wave id: c1 base = ty*16
    float acc[4][16];
    #pragma unroll
    for (int cc = 0; cc < 16; ++cc) {
        float bv = b1[ty * 16 + cc];
        #pragma unroll
        for (int ci = 0; ci < 4; ++ci) acc[ci][cc] = bv;
    }

    for (int c0 = 0; c0 < 32; ++c0) {
        float yv[3][6];
        #pragma unroll
        for (int r = 0; r < 6; ++r) {
            const float* row = &y0s[c0 * 396 + r * 66 + lane];
            yv[0][r] = row[0];
            yv[1][r] = row[1];
            yv[2][r] = row[2];
        }
        #pragma unroll
        for (int ki = 0; ki < 3; ++ki) {
            #pragma unroll
            for (int kj = 0; kj < 3; ++kj) {
                const float4* wp =
                    (const float4*)(w1t + ((c0 * 3 + ki) * 3 + kj) * 64 + ty * 16);
                #pragma unroll
                for (int q = 0; q < 4; ++q) {
                    float4 wv = wp[q];
                    #pragma unroll
                    for (int ci = 0; ci < 4; ++ci) {
                        float y = yv[kj][ci + ki];
                        acc[ci][q * 4 + 0] = fmaf(y, wv.x, acc[ci][q * 4 + 0]);
                        acc[ci][q * 4 + 1] = fmaf(y, wv.y, acc[ci][q * 4 + 1]);
                        acc[ci][q * 4 + 2] = fmaf(y, wv.z, acc[ci][q * 4 + 2]);
                        acc[ci][q * 4 + 3] = fmaf(y, wv.w, acc[ci][q * 4 + 3]);
                    }
                }
            }
        }
    }

    // ---- store relu(x) as bf16: x[b][c1][i][j], flat k = (c1*36+i)*252+j ----
    const int j = j0 + lane;
    if (j < W1N) {
        #pragma unroll
        for (int cc = 0; cc < 16; ++cc) {
            const int c1 = ty * 16 + cc;
            #pragma unroll
            for (int ci = 0; ci < 4; ++ci) {
                int k = (c1 * H1N + i0 + ci) * W1N + j;
                xbf[(size_t)b * KCNN + k] =
                    __float2bfloat16(fmaxf(acc[ci][cc], 0.0f));
            }
        }
    }
}

// ---------------- K2: split-K GEMM  partial[bid][b][f] = sum_k x[b,k]*wr[f,k] ----------------
// 284 blocks x 2048 k. LDS-staged chunks of 128 k. Threads: ks=wave (k phase),
// pair=(bg 0..7)x(fg 0..7): 4 b x 5 f register tile.
__global__ __launch_bounds__(256) void k2_gemm(
        const __hip_bfloat16* __restrict__ xbf, const float* __restrict__ wr,
        float* __restrict__ partial) {
    __shared__ float lds[9504];       // Xs 32x132 (4224) + Ws 40x132 (5280)
    float* Xs = lds;
    float* Ws = lds + 4224;

    const int tid   = threadIdx.x;
    const int bid   = blockIdx.x;
    const int kbase = bid * KPB;
    const int kcnt  = min(KPB, KCNN - kbase);   // 2048 or 1024 (last block)
    const int nch   = kcnt >> 7;

    const int ks   = tid >> 6;        // wave id: k phase
    const int pair = tid & 63;
    const int bg   = pair & 7;        // b group (4 b)
    const int fg   = pair >> 3;       // f group (5 f)

    float acc[4][5];
    #pragma unroll
    for (int i = 0; i < 4; ++i)
        #pragma unroll
        for (int jj = 0; jj < 5; ++jj) acc[i][jj] = 0.0f;

    const int xrow = tid >> 3;        // 0..31
    const int xcg  = tid & 7;         // 16-elem group

    for (int c = 0; c < nch; ++c) {
        const int k0 = kbase + c * 128;
        // stage X (bf16 -> f32), 16 elems per thread
        {
            const unsigned short* p =
                (const unsigned short*)xbf + (size_t)xrow * KCNN + k0 + xcg * 16;
            uint4 u0 = ((const uint4*)p)[0];
            uint4 u1 = ((const uint4*)p)[1];
            float* dst = Xs + xrow * 132 + xcg * 16;
            unsigned vs[8] = {u0.x, u0.y, u0.z, u0.w, u1.x, u1.y, u1.z, u1.w};
            #pragma unroll
            for (int e = 0; e < 8; ++e) {
                dst[2 * e + 0] = __uint_as_float(vs[e] << 16);
                dst[2 * e + 1] = __uint_as_float(vs[e] & 0xffff0000u);
            }
        }
        // stage Wr (f32), 5 float4 per thread
        #pragma unroll
        for (int s5 = 0; s5 < 5; ++s5) {
            int id  = tid + 256 * s5;             // 0..1279
            int row = id >> 5;                    // 0..39
            int q   = id & 31;
            float4 v = ((const float4*)(wr + (size_t)row * KCNN + k0))[q];
            ((float4*)(Ws + row * 132))[q] = v;
        }
        __syncthreads();

        #pragma unroll
        for (int s = 0; s < 8; ++s) {
            const int kk4 = s * 4 + ks;           // float4 index 0..31
            float4 xv[4], wv[5];
            #pragma unroll
            for (int i = 0; i < 4; ++i)
                xv[i] = ((const float4*)(Xs + (bg * 4 + i) * 132))[kk4];
            #pragma unroll
            for (int jj = 0; jj < 5; ++jj)
                wv[jj] = ((const float4*)(Ws + (fg * 5 + jj) * 132))[kk4];
            #pragma unroll
            for (int i = 0; i < 4; ++i)
                #pragma unroll
                for (int jj = 0; jj < 5; ++jj) {
                    float a = acc[i][jj];
                    a = fmaf(xv[i].x, wv[jj].x, a);
                    a = fmaf(xv[i].y, wv[jj].y, a);
                    a = fmaf(xv[i].z, wv[jj].z, a);
                    a = fmaf(xv[i].w, wv[jj].w, a);
                    acc[i][jj] = a;
                }
        }
        __syncthreads();
    }

    // reduce across the 4 k-phase waves via LDS
    #pragma unroll
    for (int i = 0; i < 4; ++i)
        #pragma unroll
        for (int jj = 0; jj < 5; ++jj)
            lds[(ks * 64 + pair) * 20 + i * 5 + jj] = acc[i][jj];
    __syncthreads();
    if (tid < 64) {
        #pragma unroll
        for (int i = 0; i < 4; ++i) {
            #pragma unroll
            for (int jj = 0; jj < 5; ++jj) {
                float s = 0.0f;
                #pragma unroll
                for (int w = 0; w < 4; ++w)
                    s += lds[(w * 64 + tid) * 20 + i * 5 + jj];
                int bb = (tid & 7) * 4 + i;
                int ff = (tid >> 3) * 5 + jj;
                partial[(size_t)bid * 1280 + bb * 40 + ff] = s;
            }
        }
    }
}

// ---------------- K3: gates = sigmoid(sum partials + br); wtd_mean via atomicAdd ----------------
__global__ void k3_gates(const float* __restrict__ partial, const float* __restrict__ br,
                         float* __restrict__ gates, float* __restrict__ out) {
    int p = blockIdx.x * 64 + threadIdx.x;        // 20 blocks -> 1280 pairs
    float s = 0.0f;
    for (int i = 0; i < NB2; ++i) s += partial[(size_t)i * 1280 + p];
    int f = p % 40;
    float g = 1.0f / (1.0f + __expf(-(s + br[f])));
    gates[p] = g;
    float fs = 2.0f * (float)(f + 1);
    atomicAdd(out + 51200, g * fs * (1.0f / 1280.0f));
}

// ---------------- K4: feats (inline) -> sin/cos projection -> mods ----------------
// grid (40 f, 32 b), 320 threads: h = tid>>3 (0..39), wl = tid&7 covers w.
__global__ __launch_bounds__(320) void k4_mods(
        const float* __restrict__ inp, const float* __restrict__ wf,
        const float* __restrict__ bfp, const float* __restrict__ gates,
        float* __restrict__ out) {
    const int f = blockIdx.x, b = blockIdx.y;
    const int tid = threadIdx.x;
    const int h  = tid >> 3;
    const int wl = tid & 7;
    float wfv[5];
    #pragma unroll
    for (int t = 0; t < 5; ++t) wfv[t] = wf[t];
    const float bias = bfp[0];
    // phase = 2*pi*fs*t = 2*pi*(f+1)*w/255
    const float cph = 6.283185307179586f * (float)(f + 1) / 255.0f;
    const float* row = inp + (b * HH + h) * WW;
    float sa = 0.0f, ca = 0.0f;
    for (int m = 0; m < 32; ++m) {
        int w = wl + 8 * m;
        float feat = bias;
        #pragma unroll
        for (int d = -2; d <= 2; ++d) {
            int wc = w + d;
            if (wc >= 0 && wc < WW) feat = fmaf(row[wc], wfv[d + 2], feat);
        }
        float sv, cv;
        __sincosf(cph * (float)w, &sv, &cv);
        sa = fmaf(sv, feat, sa);
        ca = fmaf(cv, feat, ca);
    }
    #pragma unroll
    for (int off = 4; off >= 1; off >>= 1) {
        sa += __shfl_xor(sa, off, 8);
        ca += __shfl_xor(ca, off, 8);
    }
    if (wl == 0) {
        float mag = sqrtf(sa * sa + ca * ca) * (1.0f / 256.0f);
        out[b * 1600 + f * 40 + h] = mag * gates[b * 40 + f];
    }
}

extern "C" void kernel_launch(void* const* d_in, const int* in_sizes, int n_in,
                              void* d_out, int out_size, void* d_ws, size_t ws_size,
                              hipStream_t stream) {
    const float* inp = (const float*)d_in[0];
    const float* w0  = (const float*)d_in[1];
    const float* b0  = (const float*)d_in[2];
    const float* w1  = (const float*)d_in[3];
    const float* b1  = (const float*)d_in[4];
    const float* wf  = (const float*)d_in[5];
    const float* bf_ = (const float*)d_in[6];
    const float* wr  = (const float*)d_in[7];
    const float* br  = (const float*)d_in[8];
    float* out = (float*)d_out;

    char* ws = (char*)d_ws;
    __hip_bfloat16* xbf = (__hip_bfloat16*)ws;            // 32*580608*2 = 37,158,912 B
    float* w1t     = (float*)(ws + 37158912);             // 73,728 B
    float* partial = (float*)(ws + 37232640);             // 284*1280*4 = 1,454,080 B
    float* gates   = (float*)(ws + 38686720);             // 5,120 B

    k0_transpose_w1<<<72, 256, 0, stream>>>(w1, w1t);
    k1_conv<<<dim3(4, 9, 32), 256, 0, stream>>>(inp, w0, b0, w1t, b1, xbf);
    k2_gemm<<<NB2, 256, 0, stream>>>(xbf, wr, partial);
    hipMemsetAsync(out + 51200, 0, 4, stream);            // zero wtd_mean accumulator
    k3_gates<<<20, 64, 0, stream>>>(partial, br, gates, out);
    k4_mods<<<dim3(40, 32), 320, 0, stream>>>(inp, wf, bf_, gates, out);
}

// Round 2
// 370.470 us; speedup vs baseline: 1.2365x; 1.2365x over previous
//
#include <hip/hip_runtime.h>
#include <hip/hip_bf16.h>
#include <math.h>

// Problem constants
#define BB   32
#define HH   40
#define WW   256
#define NF   40          // FREQ
#define H1N  36
#define W1N  252
#define KCNN 580608      // 64*36*252
#define NB2  284         // gemm split-K blocks
#define KPB  2048        // k per gemm block

// ---------------- K0: transpose w1 [c1][c0][ki][kj] -> w1t [c0][ki][kj][c1] ----------------
__global__ void k0_transpose_w1(const float* __restrict__ w1, float* __restrict__ w1t) {
    int o = blockIdx.x * 256 + threadIdx.x;      // 72*256 = 18432 = 32*9*64
    int c1 = o & 63;
    int rest = o >> 6;                            // ((c0*3+ki)*3+kj)
    int kj = rest % 3;
    int ki = (rest / 3) % 3;
    int c0 = rest / 9;
    w1t[o] = w1[(c1 * 32 + c0) * 9 + ki * 3 + kj];
}

// ---------------- K1: fused conv0(relu) + conv1(relu) -> x (bf16) ----------------
// grid (4 j-tiles, 9 i-tiles, 32 b), block 256 (4 waves).
// LDS: input tile [8][68] f32 (2176 B) + y0 tile [32 c0][6 rows][66 cols] f32 (50688 B)
// = 52864 B -> 3 blocks/CU.
// Weights are loaded via wave-uniform addresses (readfirstlane on wave id) so the
// compiler emits s_load (scalar cache) instead of 36 vector global loads per c0-iter
// -- that L1-thrashing load latency was round 1's 62% stall.
__global__ __launch_bounds__(256) void k1_conv(
        const float* __restrict__ inp, const float* __restrict__ w0,
        const float* __restrict__ b0, const float* __restrict__ w1t,
        const float* __restrict__ b1, __hip_bfloat16* __restrict__ xbf) {
    __shared__ float y0s[32 * 396];   // 396 = 6*66
    __shared__ float ins[8 * 68];

    const int jt = blockIdx.x;        // 0..3  -> j0 = 64*jt
    const int it = blockIdx.y;        // 0..8  -> i0 = 4*it
    const int b  = blockIdx.z;
    const int i0 = it * 4;
    const int j0 = jt * 64;
    const int tid = threadIdx.x;

    // ---- stage input tile rows i0..i0+7, cols j0..j0+67 (zero past W) ----
    for (int s = tid; s < 544; s += 256) {
        int r = s / 68, c = s - r * 68;
        int gc = j0 + c;
        ins[s] = (gc < WW) ? inp[(b * HH + i0 + r) * WW + gc] : 0.0f;
    }
    __syncthreads();

    // ---- conv0: y0 = relu(conv0 + b0) for rows i0..i0+5, cols j0..j0+65 ----
    {
        const int c0  = tid >> 3;     // 0..31
        const int sub = tid & 7;
        float wreg[9];
        #pragma unroll
        for (int k = 0; k < 9; ++k) wreg[k] = w0[c0 * 9 + k];
        const float bias = b0[c0];
        #pragma unroll
        for (int r = 0; r < 6; ++r) {
            for (int col = sub; col < 66; col += 8) {
                float v = 0.0f;
                if (j0 + col < 254) {              // valid conv0 output col
                    float a = bias;
                    #pragma unroll
                    for (int ki = 0; ki < 3; ++ki)
                        #pragma unroll
                        for (int kj = 0; kj < 3; ++kj)
                            a = fmaf(ins[(r + ki) * 68 + col + kj], wreg[ki * 3 + kj], a);
                    v = fmaxf(a, 0.0f);
                }
                y0s[c0 * 396 + r * 66 + col] = v;
            }
        }
    }
    __syncthreads();

    // ---- conv1 main loop: wave owns 16 output channels ----
    const int lane = tid & 63;
    const int ty   = __builtin_amdgcn_readfirstlane(tid >> 6);  // wave-uniform!
    float acc[4][16];
    #pragma unroll
    for (int cc = 0; cc < 16; ++cc) {
        float bv = b1[ty * 16 + cc];               // scalar load
        #pragma unroll
        for (int ci = 0; ci < 4; ++ci) acc[ci][cc] = bv;
    }

    for (int c0 = 0; c0 < 32; ++c0) {
        float yv[3][6];
        #pragma unroll
        for (int r = 0; r < 6; ++r) {
            const float* row = &y0s[c0 * 396 + r * 66 + lane];
            yv[0][r] = row[0];
            yv[1][r] = row[1];
            yv[2][r] = row[2];
        }
        #pragma unroll
        for (int ki = 0; ki < 3; ++ki) {
            #pragma unroll
            for (int kj = 0; kj < 3; ++kj) {
                const float4* wp =
                    (const float4*)(w1t + ((c0 * 3 + ki) * 3 + kj) * 64 + ty * 16);
                #pragma unroll
                for (int q = 0; q < 4; ++q) {
                    float4 wv = wp[q];             // s_load: all of (c0,ki,kj,ty,q) uniform
                    #pragma unroll
                    for (int ci = 0; ci < 4; ++ci) {
                        float y = yv[kj][ci + ki];
                        acc[ci][q * 4 + 0] = fmaf(y, wv.x, acc[ci][q * 4 + 0]);
                        acc[ci][q * 4 + 1] = fmaf(y, wv.y, acc[ci][q * 4 + 1]);
                        acc[ci][q * 4 + 2] = fmaf(y, wv.z, acc[ci][q * 4 + 2]);
                        acc[ci][q * 4 + 3] = fmaf(y, wv.w, acc[ci][q * 4 + 3]);
                    }
                }
            }
        }
    }

    // ---- store relu(x) as bf16: x[b][c1][i][j], flat k = (c1*36+i)*252+j ----
    const int j = j0 + lane;
    if (j < W1N) {
        #pragma unroll
        for (int cc = 0; cc < 16; ++cc) {
            const int c1 = ty * 16 + cc;
            #pragma unroll
            for (int ci = 0; ci < 4; ++ci) {
                int k = (c1 * H1N + i0 + ci) * W1N + j;
                xbf[(size_t)b * KCNN + k] =
                    __float2bfloat16(fmaxf(acc[ci][cc], 0.0f));
            }
        }
    }
}

// ---------------- K2: split-K GEMM  partial[bid][b][f] = sum_k x[b,k]*wr[f,k] ----------------
// 284 blocks x 2048 k, 128-k chunks staged in LDS. Software-pipelined: chunk c+1 is
// loaded into registers right after the LDS write of chunk c, so its HBM latency
// overlaps the compute phase instead of being exposed at the next barrier.
__global__ __launch_bounds__(256) void k2_gemm(
        const __hip_bfloat16* __restrict__ xbf, const float* __restrict__ wr,
        float* __restrict__ partial) {
    __shared__ float lds[9504];       // Xs 32x132 (4224) + Ws 40x132 (5280)
    float* Xs = lds;
    float* Ws = lds + 4224;

    const int tid   = threadIdx.x;
    const int bid   = blockIdx.x;
    const int kbase = bid * KPB;
    const int kcnt  = min(KPB, KCNN - kbase);   // 2048 or 1024 (last block)
    const int nch   = kcnt >> 7;

    const int ks   = tid >> 6;        // wave id: k phase
    const int pair = tid & 63;
    const int bg   = pair & 7;        // b group (4 b)
    const int fg   = pair >> 3;       // f group (5 f)

    float acc[4][5];
    #pragma unroll
    for (int i = 0; i < 4; ++i)
        #pragma unroll
        for (int jj = 0; jj < 5; ++jj) acc[i][jj] = 0.0f;

    const int xrow = tid >> 3;        // 0..31
    const int xcg  = tid & 7;         // 16-elem group
    const unsigned short* xp =
        (const unsigned short*)xbf + (size_t)xrow * KCNN + kbase + xcg * 16;

    int wrow[5], wq[5];
    #pragma unroll
    for (int s5 = 0; s5 < 5; ++s5) {
        int id = tid + 256 * s5;                  // 0..1279
        wrow[s5] = id >> 5;                       // 0..39
        wq[s5]   = id & 31;
    }

    // prefetch chunk 0
    uint4 xu0 = ((const uint4*)xp)[0];
    uint4 xu1 = ((const uint4*)xp)[1];
    float4 wreg[5];
    #pragma unroll
    for (int s5 = 0; s5 < 5; ++s5)
        wreg[s5] = ((const float4*)(wr + (size_t)wrow[s5] * KCNN + kbase))[wq[s5]];

    for (int c = 0; c < nch; ++c) {
        __syncthreads();              // previous compute done; safe to overwrite LDS
        {
            float* dst = Xs + xrow * 132 + xcg * 16;
            unsigned vs[8] = {xu0.x, xu0.y, xu0.z, xu0.w, xu1.x, xu1.y, xu1.z, xu1.w};
            #pragma unroll
            for (int e = 0; e < 8; ++e) {
                dst[2 * e + 0] = __uint_as_float(vs[e] << 16);
                dst[2 * e + 1] = __uint_as_float(vs[e] & 0xffff0000u);
            }
        }
        #pragma unroll
        for (int s5 = 0; s5 < 5; ++s5)
            ((float4*)(Ws + wrow[s5] * 132))[wq[s5]] = wreg[s5];
        __syncthreads();

        if (c + 1 < nch) {            // issue next chunk's loads; wait lands next iter
            const unsigned short* p2 = xp + (c + 1) * 128;
            xu0 = ((const uint4*)p2)[0];
            xu1 = ((const uint4*)p2)[1];
            #pragma unroll
            for (int s5 = 0; s5 < 5; ++s5)
                wreg[s5] = ((const float4*)(wr + (size_t)wrow[s5] * KCNN + kbase
                                            + (c + 1) * 128))[wq[s5]];
        }

        #pragma unroll
        for (int s = 0; s < 8; ++s) {
            const int kk4 = s * 4 + ks;           // float4 index 0..31
            float4 xv[4], wv[5];
            #pragma unroll
            for (int i = 0; i < 4; ++i)
                xv[i] = ((const float4*)(Xs + (bg * 4 + i) * 132))[kk4];
            #pragma unroll
            for (int jj = 0; jj < 5; ++jj)
                wv[jj] = ((const float4*)(Ws + (fg * 5 + jj) * 132))[kk4];
            #pragma unroll
            for (int i = 0; i < 4; ++i)
                #pragma unroll
                for (int jj = 0; jj < 5; ++jj) {
                    float a = acc[i][jj];
                    a = fmaf(xv[i].x, wv[jj].x, a);
                    a = fmaf(xv[i].y, wv[jj].y, a);
                    a = fmaf(xv[i].z, wv[jj].z, a);
                    a = fmaf(xv[i].w, wv[jj].w, a);
                    acc[i][jj] = a;
                }
        }
    }
    __syncthreads();

    // reduce across the 4 k-phase waves via LDS
    #pragma unroll
    for (int i = 0; i < 4; ++i)
        #pragma unroll
        for (int jj = 0; jj < 5; ++jj)
            lds[(ks * 64 + pair) * 20 + i * 5 + jj] = acc[i][jj];
    __syncthreads();
    if (tid < 64) {
        #pragma unroll
        for (int i = 0; i < 4; ++i) {
            #pragma unroll
            for (int jj = 0; jj < 5; ++jj) {
                float s = 0.0f;
                #pragma unroll
                for (int w = 0; w < 4; ++w)
                    s += lds[(w * 64 + tid) * 20 + i * 5 + jj];
                int bb = (tid & 7) * 4 + i;
                int ff = (tid >> 3) * 5 + jj;
                partial[(size_t)bid * 1280 + bb * 40 + ff] = s;
            }
        }
    }
}

// ---------------- K3: gates = sigmoid(sum partials + br); wtd_mean via atomicAdd ----------------
// 4-way k-split per block + LDS reduce (round 1 looped 284 serially per thread).
__global__ __launch_bounds__(256) void k3_gates(
        const float* __restrict__ partial, const float* __restrict__ br,
        float* __restrict__ gates, float* __restrict__ out) {
    __shared__ float red[256];
    const int p  = blockIdx.x * 64 + (threadIdx.x & 63);   // 20 blocks -> 1280 pairs
    const int ks = threadIdx.x >> 6;
    float s = 0.0f;
    for (int i = ks; i < NB2; i += 4) s += partial[(size_t)i * 1280 + p];
    red[threadIdx.x] = s;
    __syncthreads();
    if (threadIdx.x < 64) {
        s = red[threadIdx.x] + red[threadIdx.x + 64] +
            red[threadIdx.x + 128] + red[threadIdx.x + 192];
        int f = p % 40;
        float g = 1.0f / (1.0f + __expf(-(s + br[f])));
        gates[p] = g;
        float fs = 2.0f * (float)(f + 1);
        atomicAdd(out + 51200, g * fs * (1.0f / 1280.0f));
    }
}

// ---------------- K4: feats (inline) -> sin/cos projection -> mods ----------------
__global__ __launch_bounds__(320) void k4_mods(
        const float* __restrict__ inp, const float* __restrict__ wf,
        const float* __restrict__ bfp, const float* __restrict__ gates,
        float* __restrict__ out) {
    const int f = blockIdx.x, b = blockIdx.y;
    const int tid = threadIdx.x;
    const int h  = tid >> 3;
    const int wl = tid & 7;
    float wfv[5];
    #pragma unroll
    for (int t = 0; t < 5; ++t) wfv[t] = wf[t];
    const float bias = bfp[0];
    const float cph = 6.283185307179586f * (float)(f + 1) / 255.0f;
    const float* row = inp + (b * HH + h) * WW;
    float sa = 0.0f, ca = 0.0f;
    for (int m = 0; m < 32; ++m) {
        int w = wl + 8 * m;
        float feat = bias;
        #pragma unroll
        for (int d = -2; d <= 2; ++d) {
            int wc = w + d;
            if (wc >= 0 && wc < WW) feat = fmaf(row[wc], wfv[d + 2], feat);
        }
        float sv, cv;
        __sincosf(cph * (float)w, &sv, &cv);
        sa = fmaf(sv, feat, sa);
        ca = fmaf(cv, feat, ca);
    }
    #pragma unroll
    for (int off = 4; off >= 1; off >>= 1) {
        sa += __shfl_xor(sa, off, 8);
        ca += __shfl_xor(ca, off, 8);
    }
    if (wl == 0) {
        float mag = sqrtf(sa * sa + ca * ca) * (1.0f / 256.0f);
        out[b * 1600 + f * 40 + h] = mag * gates[b * 40 + f];
    }
}

extern "C" void kernel_launch(void* const* d_in, const int* in_sizes, int n_in,
                              void* d_out, int out_size, void* d_ws, size_t ws_size,
                              hipStream_t stream) {
    const float* inp = (const float*)d_in[0];
    const float* w0  = (const float*)d_in[1];
    const float* b0  = (const float*)d_in[2];
    const float* w1  = (const float*)d_in[3];
    const float* b1  = (const float*)d_in[4];
    const float* wf  = (const float*)d_in[5];
    const float* bf_ = (const float*)d_in[6];
    const float* wr  = (const float*)d_in[7];
    const float* br  = (const float*)d_in[8];
    float* out = (float*)d_out;

    char* ws = (char*)d_ws;
    __hip_bfloat16* xbf = (__hip_bfloat16*)ws;            // 32*580608*2 = 37,158,912 B
    float* w1t     = (float*)(ws + 37158912);             // 73,728 B
    float* partial = (float*)(ws + 37232640);             // 284*1280*4 = 1,454,080 B
    float* gates   = (float*)(ws + 38686720);             // 5,120 B

    k0_transpose_w1<<<72, 256, 0, stream>>>(w1, w1t);
    k1_conv<<<dim3(4, 9, 32), 256, 0, stream>>>(inp, w0, b0, w1t, b1, xbf);
    k2_gemm<<<NB2, 256, 0, stream>>>(xbf, wr, partial);
    hipMemsetAsync(out + 51200, 0, 4, stream);            // zero wtd_mean accumulator
    k3_gates<<<20, 256, 0, stream>>>(partial, br, gates, out);
    k4_mods<<<dim3(40, 32), 320, 0, stream>>>(inp, wf, bf_, gates, out);
}

// Round 3
// 365.656 us; speedup vs baseline: 1.2527x; 1.0132x over previous
//
#include <hip/hip_runtime.h>
#include <hip/hip_bf16.h>
#include <math.h>

// Problem constants
#define BB   32
#define HH   40
#define WW   256
#define NF   40          // FREQ
#define H1N  36
#define W1N  252
#define KCNN 580608      // 64*36*252
#define NB2  567         // gemm split-K blocks (567*1024 == KCNN exactly)
#define KPB  1024        // k per gemm block

typedef __attribute__((ext_vector_type(8))) short bf16x8;   // 8 bf16 = 4 VGPRs
typedef __attribute__((ext_vector_type(4))) float f32x4;    // MFMA C/D

static __device__ __forceinline__ unsigned short f2bf(float v) {
    __hip_bfloat16 h = __float2bfloat16(v);
    return *(unsigned short*)&h;
}

// ---------------- K0: w1 [c1][c0][ki][kj] f32 -> w1c [tap][c1][c0] bf16 ----------------
__global__ void k0_prep_w1(const float* __restrict__ w1, unsigned short* __restrict__ w1c) {
    int o = blockIdx.x * 256 + threadIdx.x;   // 72*256 = 18432 = 9*64*32
    int c0  = o & 31;
    int c1  = (o >> 5) & 63;
    int tap = o >> 11;                        // 0..8
    w1c[o] = f2bf(w1[(c1 * 32 + c0) * 9 + tap]);
}

// ---------------- K1: fused conv0(relu) + conv1(relu) via bf16 MFMA -> x (bf16) --------
// grid (4 jt, 9 it, 32 b), block 256 (4 waves). Wave w owns output row i0+w,
// 64 j-positions, all 64 channels.
// conv1 = 9 tap-GEMMs, K=32 (=c0): A = w1c frags (global, L2-hot, 16B/lane),
// B = y0T frags (LDS, ds_read_b128, wave reads 1KB contiguous -> conflict-free),
// D[ch][pos] in 16 accumulators (m89 layout: row=quad*4+reg, col=lane&15).
__global__ __launch_bounds__(256) void k1_conv(
        const float* __restrict__ inp, const float* __restrict__ w0,
        const float* __restrict__ b0, const unsigned short* __restrict__ w1c,
        const float* __restrict__ b1, unsigned short* __restrict__ xbf) {
    __shared__ float ins[8 * 68];                       // input tile
    __shared__ __align__(16) unsigned short y0T[396 * 32];  // y0 bf16, [pos][c0]

    const int jt = blockIdx.x;        // j0 = 64*jt
    const int it = blockIdx.y;        // i0 = 4*it
    const int b  = blockIdx.z;
    const int i0 = it * 4;
    const int j0 = jt * 64;
    const int tid = threadIdx.x;

    // ---- stage input rows i0..i0+7, cols j0..j0+67 ----
    for (int s = tid; s < 544; s += 256) {
        int r = s / 68, c = s - r * 68;
        int gc = j0 + c;
        ins[s] = (gc < WW) ? inp[(b * HH + i0 + r) * WW + gc] : 0.0f;
    }
    __syncthreads();

    // ---- conv0 -> y0T bf16 [pos][c0]: lanes = 32 c0 x 2 pos -> contiguous 128B writes
    {
        const int c0 = tid & 31;
        const int pg = tid >> 5;      // 0..7
        float wreg[9];
        #pragma unroll
        for (int k = 0; k < 9; ++k) wreg[k] = w0[c0 * 9 + k];
        const float bias = b0[c0];
        for (int it2 = 0; it2 < 50; ++it2) {
            int pos = it2 * 8 + pg;   // 0..399
            if (pos < 396) {
                int r   = pos / 66;
                int col = pos - r * 66;
                float v = 0.0f;
                if (j0 + col < 254) {     // valid conv0 output col
                    float a = bias;
                    #pragma unroll
                    for (int ki = 0; ki < 3; ++ki)
                        #pragma unroll
                        for (int kj = 0; kj < 3; ++kj)
                            a = fmaf(ins[(r + ki) * 68 + col + kj], wreg[ki * 3 + kj], a);
                    v = fmaxf(a, 0.0f);
                }
                y0T[pos * 32 + c0] = f2bf(v);
            }
        }
    }
    __syncthreads();

    // ---- conv1 MFMA main loop ----
    const int w    = tid >> 6;        // wave id -> output row i0+w
    const int lane = tid & 63;
    const int l15  = lane & 15;
    const int quad = lane >> 4;

    float biasr[4][4];                // [mt][reg]: b1[mt*16 + quad*4 + reg]
    #pragma unroll
    for (int mt = 0; mt < 4; ++mt)
        #pragma unroll
        for (int rg = 0; rg < 4; ++rg)
            biasr[mt][rg] = b1[mt * 16 + quad * 4 + rg];

    f32x4 acc[4][4];                  // [mt(ch)][nt(pos)]
    #pragma unroll
    for (int mt = 0; mt < 4; ++mt)
        #pragma unroll
        for (int nt = 0; nt < 4; ++nt)
            acc[mt][nt] = (f32x4){0.f, 0.f, 0.f, 0.f};

    #pragma unroll
    for (int ki = 0; ki < 3; ++ki) {
        #pragma unroll
        for (int kj = 0; kj < 3; ++kj) {
            const int tap = ki * 3 + kj;
            bf16x8 af[4], bfr[4];
            #pragma unroll
            for (int mt = 0; mt < 4; ++mt)   // A[m=c1][k=c0]: 16B contiguous, L2-hot
                af[mt] = *(const bf16x8*)(w1c + ((tap * 64 + mt * 16 + l15) * 32 + quad * 8));
            #pragma unroll
            for (int nt = 0; nt < 4; ++nt)   // B[k=c0][n=pos]: LDS 16B contiguous
                bfr[nt] = *(const bf16x8*)(y0T + (((w + ki) * 66 + nt * 16 + l15 + kj) * 32 + quad * 8));
            #pragma unroll
            for (int mt = 0; mt < 4; ++mt)
                #pragma unroll
                for (int nt = 0; nt < 4; ++nt)
                    acc[mt][nt] = __builtin_amdgcn_mfma_f32_16x16x32_bf16(
                        af[mt], bfr[nt], acc[mt][nt], 0, 0, 0);
        }
    }

    // ---- store relu(x+b1) bf16: D row=ch=mt*16+quad*4+rg, col=pos=nt*16+l15 ----
    const int irow = i0 + w;
    #pragma unroll
    for (int nt = 0; nt < 4; ++nt) {
        const int j = j0 + nt * 16 + l15;
        if (j < W1N) {
            #pragma unroll
            for (int mt = 0; mt < 4; ++mt) {
                #pragma unroll
                for (int rg = 0; rg < 4; ++rg) {
                    int c1 = mt * 16 + quad * 4 + rg;
                    float v = fmaxf(acc[mt][nt][rg] + biasr[mt][rg], 0.0f);
                    xbf[(size_t)b * KCNN + (c1 * H1N + irow) * W1N + j] = f2bf(v);
                }
            }
        }
    }
}

// ---------------- K2: split-K GEMM, atomic accumulate gacc[b][f] ----------------
// 567 blocks (2.2 waves/SIMD vs round-2's 1.1) x 1024 k, 128-k LDS chunks,
// register-prefetch pipeline. Ends with per-block atomicAdd into gacc[1280].
__global__ __launch_bounds__(256) void k2_gemm(
        const unsigned short* __restrict__ xbf, const float* __restrict__ wr,
        float* __restrict__ gacc) {
    __shared__ float lds[9504];       // Xs 32x132 (4224) + Ws 40x132 (5280)
    float* Xs = lds;
    float* Ws = lds + 4224;

    const int tid   = threadIdx.x;
    const int bid   = blockIdx.x;
    const int kbase = bid * KPB;
    const int nch   = KPB >> 7;       // 8

    const int ks   = tid >> 6;        // wave id: k phase
    const int pair = tid & 63;
    const int bg   = pair & 7;        // b group (4 b)
    const int fg   = pair >> 3;       // f group (5 f)

    float acc[4][5];
    #pragma unroll
    for (int i = 0; i < 4; ++i)
        #pragma unroll
        for (int jj = 0; jj < 5; ++jj) acc[i][jj] = 0.0f;

    const int xrow = tid >> 3;        // 0..31
    const int xcg  = tid & 7;
    const unsigned short* xp = xbf + (size_t)xrow * KCNN + kbase + xcg * 16;

    int wrow[5], wq[5];
    #pragma unroll
    for (int s5 = 0; s5 < 5; ++s5) {
        int id = tid + 256 * s5;
        wrow[s5] = id >> 5;
        wq[s5]   = id & 31;
    }

    uint4 xu0 = ((const uint4*)xp)[0];
    uint4 xu1 = ((const uint4*)xp)[1];
    float4 wreg[5];
    #pragma unroll
    for (int s5 = 0; s5 < 5; ++s5)
        wreg[s5] = ((const float4*)(wr + (size_t)wrow[s5] * KCNN + kbase))[wq[s5]];

    for (int c = 0; c < nch; ++c) {
        __syncthreads();
        {
            float* dst = Xs + xrow * 132 + xcg * 16;
            unsigned vs[8] = {xu0.x, xu0.y, xu0.z, xu0.w, xu1.x, xu1.y, xu1.z, xu1.w};
            #pragma unroll
            for (int e = 0; e < 8; ++e) {
                dst[2 * e + 0] = __uint_as_float(vs[e] << 16);
                dst[2 * e + 1] = __uint_as_float(vs[e] & 0xffff0000u);
            }
        }
        #pragma unroll
        for (int s5 = 0; s5 < 5; ++s5)
            ((float4*)(Ws + wrow[s5] * 132))[wq[s5]] = wreg[s5];
        __syncthreads();

        if (c + 1 < nch) {
            const unsigned short* p2 = xp + (c + 1) * 128;
            xu0 = ((const uint4*)p2)[0];
            xu1 = ((const uint4*)p2)[1];
            #pragma unroll
            for (int s5 = 0; s5 < 5; ++s5)
                wreg[s5] = ((const float4*)(wr + (size_t)wrow[s5] * KCNN + kbase
                                            + (c + 1) * 128))[wq[s5]];
        }

        #pragma unroll
        for (int s = 0; s < 8; ++s) {
            const int kk4 = s * 4 + ks;
            float4 xv[4], wv[5];
            #pragma unroll
            for (int i = 0; i < 4; ++i)
                xv[i] = ((const float4*)(Xs + (bg * 4 + i) * 132))[kk4];
            #pragma unroll
            for (int jj = 0; jj < 5; ++jj)
                wv[jj] = ((const float4*)(Ws + (fg * 5 + jj) * 132))[kk4];
            #pragma unroll
            for (int i = 0; i < 4; ++i)
                #pragma unroll
                for (int jj = 0; jj < 5; ++jj) {
                    float a = acc[i][jj];
                    a = fmaf(xv[i].x, wv[jj].x, a);
                    a = fmaf(xv[i].y, wv[jj].y, a);
                    a = fmaf(xv[i].z, wv[jj].z, a);
                    a = fmaf(xv[i].w, wv[jj].w, a);
                    acc[i][jj] = a;
                }
        }
    }
    __syncthreads();

    // reduce 4 k-phase waves via LDS, then atomic into gacc
    #pragma unroll
    for (int i = 0; i < 4; ++i)
        #pragma unroll
        for (int jj = 0; jj < 5; ++jj)
            lds[(ks * 64 + pair) * 20 + i * 5 + jj] = acc[i][jj];
    __syncthreads();
    if (tid < 64) {
        #pragma unroll
        for (int i = 0; i < 4; ++i) {
            #pragma unroll
            for (int jj = 0; jj < 5; ++jj) {
                float s = 0.0f;
                #pragma unroll
                for (int w = 0; w < 4; ++w)
                    s += lds[(w * 64 + tid) * 20 + i * 5 + jj];
                int bb = (tid & 7) * 4 + i;
                int ff = (tid >> 3) * 5 + jj;
                atomicAdd(&gacc[bb * 40 + ff], s);
            }
        }
    }
}

// ---------------- K3: gates = sigmoid(gacc + br); wtd_mean atomic ----------------
__global__ void k3_gates(const float* __restrict__ gacc, const float* __restrict__ br,
                         float* __restrict__ gates, float* __restrict__ out) {
    int p = blockIdx.x * 64 + threadIdx.x;    // 20 blocks -> 1280
    int f = p % 40;
    float g = 1.0f / (1.0f + __expf(-(gacc[p] + br[f])));
    gates[p] = g;
    float fs = 2.0f * (float)(f + 1);
    atomicAdd(out + 51200, g * fs * (1.0f / 1280.0f));
}

// ---------------- K4: feats (inline) -> sin/cos projection -> mods ----------------
__global__ __launch_bounds__(320) void k4_mods(
        const float* __restrict__ inp, const float* __restrict__ wf,
        const float* __restrict__ bfp, const float* __restrict__ gates,
        float* __restrict__ out) {
    const int f = blockIdx.x, b = blockIdx.y;
    const int tid = threadIdx.x;
    const int h  = tid >> 3;
    const int wl = tid & 7;
    float wfv[5];
    #pragma unroll
    for (int t = 0; t < 5; ++t) wfv[t] = wf[t];
    const float bias = bfp[0];
    const float cph = 6.283185307179586f * (float)(f + 1) / 255.0f;
    const float* row = inp + (b * HH + h) * WW;
    float sa = 0.0f, ca = 0.0f;
    for (int m = 0; m < 32; ++m) {
        int w = wl + 8 * m;
        float feat = bias;
        #pragma unroll
        for (int d = -2; d <= 2; ++d) {
            int wc = w + d;
            if (wc >= 0 && wc < WW) feat = fmaf(row[wc], wfv[d + 2], feat);
        }
        float sv, cv;
        __sincosf(cph * (float)w, &sv, &cv);
        sa = fmaf(sv, feat, sa);
        ca = fmaf(cv, feat, ca);
    }
    #pragma unroll
    for (int off = 4; off >= 1; off >>= 1) {
        sa += __shfl_xor(sa, off, 8);
        ca += __shfl_xor(ca, off, 8);
    }
    if (wl == 0) {
        float mag = sqrtf(sa * sa + ca * ca) * (1.0f / 256.0f);
        out[b * 1600 + f * 40 + h] = mag * gates[b * 40 + f];
    }
}

extern "C" void kernel_launch(void* const* d_in, const int* in_sizes, int n_in,
                              void* d_out, int out_size, void* d_ws, size_t ws_size,
                              hipStream_t stream) {
    const float* inp = (const float*)d_in[0];
    const float* w0  = (const float*)d_in[1];
    const float* b0  = (const float*)d_in[2];
    const float* w1  = (const float*)d_in[3];
    const float* b1  = (const float*)d_in[4];
    const float* wf  = (const float*)d_in[5];
    const float* bf_ = (const float*)d_in[6];
    const float* wr  = (const float*)d_in[7];
    const float* br  = (const float*)d_in[8];
    float* out = (float*)d_out;

    char* ws = (char*)d_ws;
    unsigned short* xbf = (unsigned short*)ws;            // 37,158,912 B
    unsigned short* w1c = (unsigned short*)(ws + 37158912);  // 36,864 B
    float* gacc  = (float*)(ws + 37195776);               // 5,120 B
    float* gates = (float*)(ws + 37200896);               // 5,120 B

    k0_prep_w1<<<72, 256, 0, stream>>>(w1, w1c);
    hipMemsetAsync(gacc, 0, 1280 * 4, stream);
    hipMemsetAsync(out + 51200, 0, 4, stream);
    k1_conv<<<dim3(4, 9, 32), 256, 0, stream>>>(inp, w0, b0, w1c, b1, xbf);
    k2_gemm<<<NB2, 256, 0, stream>>>(xbf, wr, gacc);
    k3_gates<<<20, 64, 0, stream>>>(gacc, br, gates, out);
    k4_mods<<<dim3(40, 32), 320, 0, stream>>>(inp, wf, bf_, gates, out);
}

// Round 4
// 232.993 us; speedup vs baseline: 1.9660x; 1.5694x over previous
//
#include <hip/hip_runtime.h>
#include <hip/hip_bf16.h>
#include <math.h>

// Problem constants
#define BB   32
#define HH   40
#define WW   256
#define NF   40          // FREQ
#define H1N  36
#define W1N  252
#define KCNN 580608      // 64*36*252
#define NW2  2016        // k2 total waves (252 blocks x 8)
#define KPW  288         // k per wave (9 chunks x 32); 2016*288 == KCNN exactly

typedef __attribute__((ext_vector_type(8))) short bf16x8;   // 8 bf16 = 4 VGPRs
typedef __attribute__((ext_vector_type(4))) float f32x4;    // MFMA C/D

static __device__ __forceinline__ unsigned short f2bf(float v) {
    __hip_bfloat16 h = __float2bfloat16(v);
    return *(unsigned short*)&h;
}

static __device__ __forceinline__ bf16x8 packbf(float4 lo, float4 hi) {
    bf16x8 r;
    r[0] = (short)f2bf(lo.x); r[1] = (short)f2bf(lo.y);
    r[2] = (short)f2bf(lo.z); r[3] = (short)f2bf(lo.w);
    r[4] = (short)f2bf(hi.x); r[5] = (short)f2bf(hi.y);
    r[6] = (short)f2bf(hi.z); r[7] = (short)f2bf(hi.w);
    return r;
}

// ---------------- K0: w1 [c1][c0][ki][kj] f32 -> w1c [tap][c1][c0] bf16 ----------------
__global__ void k0_prep_w1(const float* __restrict__ w1, unsigned short* __restrict__ w1c) {
    int o = blockIdx.x * 256 + threadIdx.x;   // 72*256 = 18432 = 9*64*32
    int c0  = o & 31;
    int c1  = (o >> 5) & 63;
    int tap = o >> 11;                        // 0..8
    w1c[o] = f2bf(w1[(c1 * 32 + c0) * 9 + tap]);
}

// ---------------- K1: fused conv0(relu) + conv1(relu) via bf16 MFMA -> x (bf16) --------
// grid (4 jt, 9 it, 32 b), block 256 (4 waves). Wave w owns output row i0+w.
// y0T row stride padded 32 -> 40 shorts (80 B): keeps ds_read_b128 16B-aligned and
// turns the old 8-way bank conflict (64B stride) into a uniform free 2-way.
__global__ __launch_bounds__(256) void k1_conv(
        const float* __restrict__ inp, const float* __restrict__ w0,
        const float* __restrict__ b0, const unsigned short* __restrict__ w1c,
        const float* __restrict__ b1, unsigned short* __restrict__ xbf) {
    __shared__ float ins[8 * 68];                            // input tile
    __shared__ __align__(16) unsigned short y0T[396 * 40];   // y0 bf16, [pos][c0(pad 40)]

    const int jt = blockIdx.x;        // j0 = 64*jt
    const int it = blockIdx.y;        // i0 = 4*it
    const int b  = blockIdx.z;
    const int i0 = it * 4;
    const int j0 = jt * 64;
    const int tid = threadIdx.x;

    // ---- stage input rows i0..i0+7, cols j0..j0+67 ----
    for (int s = tid; s < 544; s += 256) {
        int r = s / 68, c = s - r * 68;
        int gc = j0 + c;
        ins[s] = (gc < WW) ? inp[(b * HH + i0 + r) * WW + gc] : 0.0f;
    }
    __syncthreads();

    // ---- conv0 -> y0T bf16 [pos][c0] ----
    {
        const int c0 = tid & 31;
        const int pg = tid >> 5;      // 0..7
        float wreg[9];
        #pragma unroll
        for (int k = 0; k < 9; ++k) wreg[k] = w0[c0 * 9 + k];
        const float bias = b0[c0];
        for (int it2 = 0; it2 < 50; ++it2) {
            int pos = it2 * 8 + pg;   // 0..399
            if (pos < 396) {
                int r   = pos / 66;
                int col = pos - r * 66;
                float v = 0.0f;
                if (j0 + col < 254) {     // valid conv0 output col
                    float a = bias;
                    #pragma unroll
                    for (int ki = 0; ki < 3; ++ki)
                        #pragma unroll
                        for (int kj = 0; kj < 3; ++kj)
                            a = fmaf(ins[(r + ki) * 68 + col + kj], wreg[ki * 3 + kj], a);
                    v = fmaxf(a, 0.0f);
                }
                y0T[pos * 40 + c0] = f2bf(v);
            }
        }
    }
    __syncthreads();

    // ---- conv1: 9 tap-GEMMs, K=32(c0). A = w1c (global, L2-hot), B = y0T (LDS) ----
    const int w    = tid >> 6;        // wave id -> output row i0+w
    const int lane = tid & 63;
    const int l15  = lane & 15;
    const int quad = lane >> 4;

    float biasr[4][4];                // [mt][reg]
    #pragma unroll
    for (int mt = 0; mt < 4; ++mt)
        #pragma unroll
        for (int rg = 0; rg < 4; ++rg)
            biasr[mt][rg] = b1[mt * 16 + quad * 4 + rg];

    f32x4 acc[4][4];                  // [mt(ch)][nt(pos)]
    #pragma unroll
    for (int mt = 0; mt < 4; ++mt)
        #pragma unroll
        for (int nt = 0; nt < 4; ++nt)
            acc[mt][nt] = (f32x4){0.f, 0.f, 0.f, 0.f};

    #pragma unroll
    for (int ki = 0; ki < 3; ++ki) {
        #pragma unroll
        for (int kj = 0; kj < 3; ++kj) {
            const int tap = ki * 3 + kj;
            bf16x8 af[4], bfr[4];
            #pragma unroll
            for (int mt = 0; mt < 4; ++mt)   // A[m=c1][k=c0]
                af[mt] = *(const bf16x8*)(w1c + ((tap * 64 + mt * 16 + l15) * 32 + quad * 8));
            #pragma unroll
            for (int nt = 0; nt < 4; ++nt)   // B[k=c0][n=pos]
                bfr[nt] = *(const bf16x8*)(y0T + (((w + ki) * 66 + nt * 16 + l15 + kj) * 40 + quad * 8));
            #pragma unroll
            for (int mt = 0; mt < 4; ++mt)
                #pragma unroll
                for (int nt = 0; nt < 4; ++nt)
                    acc[mt][nt] = __builtin_amdgcn_mfma_f32_16x16x32_bf16(
                        af[mt], bfr[nt], acc[mt][nt], 0, 0, 0);
        }
    }

    // ---- store relu(x+b1) bf16: D row=ch, col=pos ----
    const int irow = i0 + w;
    #pragma unroll
    for (int nt = 0; nt < 4; ++nt) {
        const int j = j0 + nt * 16 + l15;
        if (j < W1N) {
            #pragma unroll
            for (int mt = 0; mt < 4; ++mt) {
                #pragma unroll
                for (int rg = 0; rg < 4; ++rg) {
                    int c1 = mt * 16 + quad * 4 + rg;
                    float v = fmaxf(acc[mt][nt][rg] + biasr[mt][rg], 0.0f);
                    xbf[(size_t)b * KCNN + (c1 * H1N + irow) * W1N + j] = f2bf(v);
                }
            }
        }
    }
}

// ---------------- K2: barrier-free MFMA split-K GEMM -> atomic gacc[b][f] ----------------
// gacc[b][f] = sum_k x[b,k]*wr[f,k]. Each of 2016 waves owns a private 288-k slice;
// per 32-k chunk: 2 A-loads (x bf16) + 6 B-loads (wr f32 -> bf16) + 6 MFMA
// (D[m=b 2 tiles][n=f 3 tiles, third masked past f=40]). No __syncthreads in the
// k-loop; 2-deep register pipeline. End: LDS reduce 8 waves -> 1280 atomics/block.
__global__ __launch_bounds__(512) void k2_gemm(
        const unsigned short* __restrict__ xbf, const float* __restrict__ wr,
        float* __restrict__ gacc) {
    __shared__ float red[8][32][41];  // wave-partials, stride 41 breaks 4-way conflicts

    const int tid  = threadIdx.x;
    const int wv   = tid >> 6;
    const int lane = tid & 63;
    const int l15  = lane & 15;
    const int quad = lane >> 4;
    const size_t kw = (size_t)(blockIdx.x * 8 + wv) * KPW;

    const unsigned short* ap0 = xbf + (size_t)l15 * KCNN + kw + quad * 8;
    const unsigned short* ap1 = ap0 + (size_t)16 * KCNN;
    const float* bp0 = wr + (size_t)l15 * KCNN + kw + quad * 8;
    const float* bp1 = bp0 + (size_t)16 * KCNN;
    const bool v2 = (l15 < 8);
    const float* bp2 = bp0 + (size_t)32 * KCNN;   // only dereferenced when v2

    f32x4 acc[2][3];
    #pragma unroll
    for (int mt = 0; mt < 2; ++mt)
        #pragma unroll
        for (int nt = 0; nt < 3; ++nt)
            acc[mt][nt] = (f32x4){0.f, 0.f, 0.f, 0.f};

    const float4 fz = {0.f, 0.f, 0.f, 0.f};
    bf16x8 a0c, a1c, a0n, a1n;
    float4 bw[3][2], bwn[3][2];

    // preload chunk 0
    a0c = *(const bf16x8*)ap0;
    a1c = *(const bf16x8*)ap1;
    bw[0][0] = *(const float4*)bp0; bw[0][1] = *(const float4*)(bp0 + 4);
    bw[1][0] = *(const float4*)bp1; bw[1][1] = *(const float4*)(bp1 + 4);
    if (v2) { bw[2][0] = *(const float4*)bp2; bw[2][1] = *(const float4*)(bp2 + 4); }
    else    { bw[2][0] = fz; bw[2][1] = fz; }

    for (int c = 0; c < 9; ++c) {
        if (c < 8) {                  // issue next chunk's loads; overlap with MFMA below
            const int o2 = (c + 1) * 32;
            a0n = *(const bf16x8*)(ap0 + o2);
            a1n = *(const bf16x8*)(ap1 + o2);
            bwn[0][0] = *(const float4*)(bp0 + o2); bwn[0][1] = *(const float4*)(bp0 + o2 + 4);
            bwn[1][0] = *(const float4*)(bp1 + o2); bwn[1][1] = *(const float4*)(bp1 + o2 + 4);
            if (v2) { bwn[2][0] = *(const float4*)(bp2 + o2); bwn[2][1] = *(const float4*)(bp2 + o2 + 4); }
            else    { bwn[2][0] = fz; bwn[2][1] = fz; }
        }
        #pragma unroll
        for (int nt = 0; nt < 3; ++nt) {
            bf16x8 bfrag = packbf(bw[nt][0], bw[nt][1]);
            acc[0][nt] = __builtin_amdgcn_mfma_f32_16x16x32_bf16(a0c, bfrag, acc[0][nt], 0, 0, 0);
            acc[1][nt] = __builtin_amdgcn_mfma_f32_16x16x32_bf16(a1c, bfrag, acc[1][nt], 0, 0, 0);
        }
        if (c < 8) {
            a0c = a0n; a1c = a1n;
            #pragma unroll
            for (int nt = 0; nt < 3; ++nt) { bw[nt][0] = bwn[nt][0]; bw[nt][1] = bwn[nt][1]; }
        }
    }

    // ---- reduce 8 waves via LDS, then atomics ----
    #pragma unroll
    for (int mt = 0; mt < 2; ++mt)
        #pragma unroll
        for (int nt = 0; nt < 3; ++nt)
            #pragma unroll
            for (int rg = 0; rg < 4; ++rg) {
                int bb = mt * 16 + quad * 4 + rg;
                int ff = nt * 16 + l15;
                if (ff < NF) red[wv][bb][ff] = acc[mt][nt][rg];
            }
    __syncthreads();
    for (int p = tid; p < 1280; p += 512) {
        int bb = p / 40, ff = p - bb * 40;
        float s = 0.0f;
        #pragma unroll
        for (int w = 0; w < 8; ++w) s += red[w][bb][ff];
        atomicAdd(gacc + p, s);
    }
}

// ---------------- K3: gates = sigmoid(gacc + br); wtd_mean atomic ----------------
__global__ void k3_gates(const float* __restrict__ gacc, const float* __restrict__ br,
                         float* __restrict__ gates, float* __restrict__ out) {
    int p = blockIdx.x * 64 + threadIdx.x;    // 20 blocks -> 1280
    int f = p % 40;
    float g = 1.0f / (1.0f + __expf(-(gacc[p] + br[f])));
    gates[p] = g;
    float fs = 2.0f * (float)(f + 1);
    atomicAdd(out + 51200, g * fs * (1.0f / 1280.0f));
}

// ---------------- K4: feats (inline) -> sin/cos projection -> mods ----------------
__global__ __launch_bounds__(320) void k4_mods(
        const float* __restrict__ inp, const float* __restrict__ wf,
        const float* __restrict__ bfp, const float* __restrict__ gates,
        float* __restrict__ out) {
    const int f = blockIdx.x, b = blockIdx.y;
    const int tid = threadIdx.x;
    const int h  = tid >> 3;
    const int wl = tid & 7;
    float wfv[5];
    #pragma unroll
    for (int t = 0; t < 5; ++t) wfv[t] = wf[t];
    const float bias = bfp[0];
    const float cph = 6.283185307179586f * (float)(f + 1) / 255.0f;
    const float* row = inp + (b * HH + h) * WW;
    float sa = 0.0f, ca = 0.0f;
    for (int m = 0; m < 32; ++m) {
        int w = wl + 8 * m;
        float feat = bias;
        #pragma unroll
        for (int d = -2; d <= 2; ++d) {
            int wc = w + d;
            if (wc >= 0 && wc < WW) feat = fmaf(row[wc], wfv[d + 2], feat);
        }
        float sv, cv;
        __sincosf(cph * (float)w, &sv, &cv);
        sa = fmaf(sv, feat, sa);
        ca = fmaf(cv, feat, ca);
    }
    #pragma unroll
    for (int off = 4; off >= 1; off >>= 1) {
        sa += __shfl_xor(sa, off, 8);
        ca += __shfl_xor(ca, off, 8);
    }
    if (wl == 0) {
        float mag = sqrtf(sa * sa + ca * ca) * (1.0f / 256.0f);
        out[b * 1600 + f * 40 + h] = mag * gates[b * 40 + f];
    }
}

extern "C" void kernel_launch(void* const* d_in, const int* in_sizes, int n_in,
                              void* d_out, int out_size, void* d_ws, size_t ws_size,
                              hipStream_t stream) {
    const float* inp = (const float*)d_in[0];
    const float* w0  = (const float*)d_in[1];
    const float* b0  = (const float*)d_in[2];
    const float* w1  = (const float*)d_in[3];
    const float* b1  = (const float*)d_in[4];
    const float* wf  = (const float*)d_in[5];
    const float* bf_ = (const float*)d_in[6];
    const float* wr  = (const float*)d_in[7];
    const float* br  = (const float*)d_in[8];
    float* out = (float*)d_out;

    char* ws = (char*)d_ws;
    unsigned short* xbf = (unsigned short*)ws;               // 37,158,912 B
    unsigned short* w1c = (unsigned short*)(ws + 37158912);  // 36,864 B
    float* gacc  = (float*)(ws + 37195776);                  // 5,120 B
    float* gates = (float*)(ws + 37200896);                  // 5,120 B

    k0_prep_w1<<<72, 256, 0, stream>>>(w1, w1c);
    hipMemsetAsync(gacc, 0, 1280 * 4, stream);
    hipMemsetAsync(out + 51200, 0, 4, stream);
    k1_conv<<<dim3(4, 9, 32), 256, 0, stream>>>(inp, w0, b0, w1c, b1, xbf);
    k2_gemm<<<252, 512, 0, stream>>>(xbf, wr, gacc);
    k3_gates<<<20, 64, 0, stream>>>(gacc, br, gates, out);
    k4_mods<<<dim3(40, 32), 320, 0, stream>>>(inp, wf, bf_, gates, out);
}